// Round 10
// baseline (144.990 us; speedup 1.0000x reference)
//
#include <hip/hip_runtime.h>

// Z: (2049, 8193) fp32, alpha: (1,) fp32.
// out = Z, except last row: out[2048,j] = Z[2048,j] + (alpha/N)*sum_{c<D} v[c]*(Z[c+D,j]-Z[c,j])
// where v[c] = sum_{j<N} Z[2048,j]*Z[c,j]   (j < N only: M kills column N)
//
// Rank-1 form: corr[j] = sum_{r<2048} w[r]*Z[r,j], w[r] = -v[r] (r<D), +v[r-D] (r>=D).
// A/B vs round 9: copy_corr tiling UNCHANGED; the 4 atomicAdds -> one private partial-row
// store (unique (by,j) writer, race-free), reduced by finalize. Isolates "atomics to d_ws"
// as the round-9 regression cause.
//  K1 vdot_rows: v[c] = dot(Z[c,:8192], Z[2048,:8192]).
//  K2 copy_corr: grid (8 j-windows x 256 row-chunks of 8 rows) x 256 thr (32 waves/CU).
//                NT-copy rows 0..2047 (j<8192) + accumulate w[r]*quad -> part[by][j].
//  K3 finalize:  out[2048,j] = Z[2048,j] + scale*sum_g part[g][j]; plus column j=8192.

#define D   1024
#define N   8192
#define DD  2049
#define N1  8193

#define PSTR    8208   // partial row stride (8192 + 16 pad: breaks 32KB power-of-2 camping)
#define WS_PART 1024   // ws floats: v[1024] | part[256][8208]  (~8.4 MB total)

typedef float f32x4u __attribute__((ext_vector_type(4), aligned(4)));   // row phase (r*8193)%4
typedef float f32x4a __attribute__((ext_vector_type(4), aligned(16)));  // provably aligned

// ---------------- K1: per-row dot ----------------
// grid = 1024 x 512 (one block per row c). u-loads aligned; row loads HW-coalesced.
__global__ void __launch_bounds__(512) vdot_rows(const float* __restrict__ Z,
                                                 float* __restrict__ ws) {
    const int c = blockIdx.x;
    const int t = threadIdx.x;
    const float* __restrict__ row = Z + (size_t)c * N1;
    const float* __restrict__ u   = Z + (size_t)(DD - 1) * N1;   // 16B-aligned
    float acc = 0.f;
    #pragma unroll
    for (int it = 0; it < 4; ++it) {
        const int q = t + it * 512;                // j = 4q..4q+3 < 8192
        f32x4u a = *(const f32x4u*)(row + 4 * q);
        f32x4a b = *(const f32x4a*)(u   + 4 * q);
        acc += a.x * b.x + a.y * b.y + a.z * b.z + a.w * b.w;
    }
    #pragma unroll
    for (int off = 32; off > 0; off >>= 1)
        acc += __shfl_down(acc, off, 64);
    __shared__ float smem[8];
    if ((t & 63) == 0) smem[t >> 6] = acc;
    __syncthreads();
    if (t == 0) {
        float s = 0.f;
        #pragma unroll
        for (int w = 0; w < 8; ++w) s += smem[w];
        ws[c] = s;                                 // v[c]
    }
}

// ---------------- K2: fused copy + correction partials (NO atomics) ----------------
// grid = (8, 256) x 256. Block (bx,by): j-window bx*1024 + t*4, rows by*8 .. by*8+7.
// Identical memory pattern to round 9 except the output: one f32x4a partial store.
__global__ void __launch_bounds__(256) copy_corr(const float* __restrict__ Z,
                                                 float* __restrict__ out,
                                                 const float* __restrict__ v,
                                                 float* __restrict__ part) {
    const int t  = threadIdx.x;
    const int j0 = blockIdx.x * 1024 + t * 4;      // < 8192
    const int r0 = blockIdx.y * 8;                 // rows r0..r0+7 (< 2048)
    __shared__ float wsm[8];
    if (t < 8) {
        const int r = r0 + t;
        wsm[t] = (r < D) ? -v[r] : v[r - D];
    }
    __syncthreads();

    const float* __restrict__ zp = Z   + (size_t)r0 * N1 + j0;
    float*       __restrict__ op = out + (size_t)r0 * N1 + j0;
    float ax = 0.f, ay = 0.f, az = 0.f, aw = 0.f;
    #pragma unroll
    for (int i = 0; i < 8; ++i) {
        f32x4u a = *(const f32x4u*)zp;
        __builtin_nontemporal_store(a, (f32x4u*)op);
        const float w = wsm[i];
        ax += w * a.x; ay += w * a.y; az += w * a.z; aw += w * a.w;
        zp += N1; op += N1;
    }
    f32x4a res = {ax, ay, az, aw};
    *(f32x4a*)(part + (size_t)blockIdx.y * PSTR + j0) = res;   // unique writer: race-free
}

// ---------------- K3: finalize last row + column j=8192 ----------------
// grid = 9 x 256. Blocks 0..7: out[2048,j] = z_last[j] + scale * sum_{g<256} part[g][j].
// Block 8: copy column j=8192 for rows 0..2047 and write out[2048][8192] with its tail.
__global__ void __launch_bounds__(256) finalize(const float* __restrict__ Z,
                                                const float* __restrict__ ws,
                                                const float* __restrict__ alpha,
                                                float* __restrict__ out) {
    const int b = blockIdx.x, t = threadIdx.x;
    const float scale = alpha[0] / (float)N;
    const float* __restrict__ zl = Z   + (size_t)(DD - 1) * N1;   // 16B-aligned
    float*       __restrict__ o  = out + (size_t)(DD - 1) * N1;
    if (b < 8) {
        const int j0 = (b * 256 + t) * 4;          // < 8192
        const float* __restrict__ pp = ws + WS_PART + j0;
        float sx = 0.f, sy = 0.f, sz = 0.f, sw = 0.f;
        #pragma unroll 8
        for (int g = 0; g < 256; ++g) {
            f32x4a p = *(const f32x4a*)(pp + (size_t)g * PSTR);
            sx += p.x; sy += p.y; sz += p.z; sw += p.w;
        }
        f32x4a zq = *(const f32x4a*)(zl + j0);
        f32x4a r = {zq.x + scale * sx, zq.y + scale * sy,
                    zq.z + scale * sz, zq.w + scale * sw};
        *(f32x4a*)(o + j0) = r;
    } else {
        float s = 0.f;
        #pragma unroll
        for (int i = 0; i < 8; ++i) {
            const int r = t * 8 + i;               // 0..2047
            const float zv = Z[(size_t)r * N1 + N];
            out[(size_t)r * N1 + N] = zv;          // column copy
            const float w = (r < D) ? -ws[r] : ws[r - D];
            s += w * zv;
        }
        #pragma unroll
        for (int off = 32; off > 0; off >>= 1)
            s += __shfl_down(s, off, 64);
        __shared__ float sm[4];
        if ((t & 63) == 0) sm[t >> 6] = s;
        __syncthreads();
        if (t == 0) {
            float tot = sm[0] + sm[1] + sm[2] + sm[3];
            o[N] = zl[N] + scale * tot;
        }
    }
}

extern "C" void kernel_launch(void* const* d_in, const int* in_sizes, int n_in,
                              void* d_out, int out_size, void* d_ws, size_t ws_size,
                              hipStream_t stream) {
    const float* Z     = (const float*)d_in[0];
    const float* alpha = (const float*)d_in[1];
    float* out = (float*)d_out;
    float* ws  = (float*)d_ws;   // v[1024] | part[256][8208]  (~8.4 MB)

    vdot_rows<<<1024, 512, 0, stream>>>(Z, ws);
    copy_corr<<<dim3(8, 256), 256, 0, stream>>>(Z, out, ws, ws + WS_PART);
    finalize <<<9, 256, 0, stream>>>(Z, ws, alpha, out);
}

// Round 11
// 126.898 us; speedup vs baseline: 1.1426x; 1.1426x over previous
//
#include <hip/hip_runtime.h>

// Z: (2049, 8193) fp32, alpha: (1,) fp32.
// out = Z, except last row: out[2048, j] += (alpha/N) * sum_{c<D} v[c]*(Z[c+D,j]-Z[c,j])
// where v[c] = sum_{j<N} Z[2048, j] * Z[c, j]   (j < N only: M kills column N)
//
// FINAL (round-6 best, 126.3 us; reverted after rounds 9/10 fusion regressions):
//  K1: per-row copy + fused dot (2049 blocks x 512). Full-row streaming at ~5.8 TB/s
//      (1.08x the 21.3 us copy floor). Row-split tilings measured SLOWER (r9/r10).
//  K2: correction, grid (64 j-windows x 32 c-splits) x 256 thr = 2048 blocks
//      = 8 blocks/CU (32 waves/CU). Measured 16.4 us by 4x-replication probe (r7).
//      Atomics to d_out measured harmless (r0/r6/r7 A/Bs).
//  Session evidence: dur = ~86 us fixed poison-fill cost + ~40 us marginal;
//  marginal sits ~95% of composed floor. Do not: cooperative launch (harness
//  unsupported, r5), fuse correction into copy (stream-efficiency loss > traffic
//  saved, r9/r10), atomic-free partials (null, r0), alignment games (null, r3).

#define D   1024
#define N   8192
#define DD  2049
#define N1  8193

typedef float f32x4u __attribute__((ext_vector_type(4), aligned(4)));  // rows start at phase (r*8193)%4

// ---------------- Kernel 1: row-parallel copy + fused dot ----------------
// grid = 2049 blocks (one per row) x 512 threads. Each thread: 4 quads (16 floats).
// Rows r < 1024 also accumulate v[r] = dot(row, u) over j=0..8191 from the SAME registers.
__global__ void __launch_bounds__(512) copy_dot_rows(const float* __restrict__ Z,
                                                     float* __restrict__ out,
                                                     float* __restrict__ v) {
    const int r = blockIdx.x;
    const int t = threadIdx.x;
    const float* __restrict__ row  = Z   + (long)r * N1;
    float*       __restrict__ orow = out + (long)r * N1;
    const float* __restrict__ u    = Z   + (long)(DD - 1) * N1;   // 16B-aligned (2048*8193 % 4 == 0)

    if (r < D) {
        float acc = 0.f;
        #pragma unroll
        for (int it = 0; it < 4; ++it) {
            const int q = t + it * 512;          // quad 0..2047 -> j = 4q..4q+3 (j<8192)
            f32x4u a = *(const f32x4u*)(row + 4 * q);
            f32x4u b = *(const f32x4u*)(u   + 4 * q);
            __builtin_nontemporal_store(a, (f32x4u*)(orow + 4 * q));
            acc += a.x * b.x + a.y * b.y + a.z * b.z + a.w * b.w;
        }
        // reduce 512 threads: wave butterfly then 8-slot LDS
        #pragma unroll
        for (int off = 32; off > 0; off >>= 1)
            acc += __shfl_down(acc, off, 64);
        __shared__ float smem[8];
        if ((t & 63) == 0) smem[t >> 6] = acc;
        __syncthreads();
        if (t == 0) {
            float s = 0.f;
            #pragma unroll
            for (int w = 0; w < 8; ++w) s += smem[w];
            v[r] = s;
        }
    } else {
        #pragma unroll
        for (int it = 0; it < 4; ++it) {
            const int q = t + it * 512;
            f32x4u a = *(const f32x4u*)(row + 4 * q);
            __builtin_nontemporal_store(a, (f32x4u*)(orow + 4 * q));
        }
    }
    if (t == 511) orow[N] = row[N];              // tail element j = 8192 of each row
}

// ---------------- Kernel 2: last-row correction, high-occupancy ----------------
// grid = (64, 32) x 256: bx = 128-dword j-window, by = 32-c split.
// Thread t: jq = t&31 (quad in window), cg = t>>5 (8 groups of 4 c's).
// 8 dwordx4 loads/thread; cg-reduce via shfl(32) + LDS; 4 atomicAdds per jq-slot.
__global__ void __launch_bounds__(256) corr_kernel(const float* __restrict__ Z,
                                                   const float* __restrict__ v,
                                                   const float* __restrict__ alpha,
                                                   float* __restrict__ out) {
    const int t  = threadIdx.x;
    const int jq = t & 31;
    const int cg = t >> 5;                         // 0..7
    const int j0 = blockIdx.x * 128 + jq * 4;
    const int cbase = blockIdx.y * 32 + cg * 4;
    const float scale = alpha[0] / (float)N;

    float ax = 0.f, ay = 0.f, az = 0.f, aw = 0.f;
    #pragma unroll
    for (int m = 0; m < 4; ++m) {
        const int c = cbase + m;
        const float vc = v[c];
        f32x4u zp = *(const f32x4u*)(Z + (size_t)(c + D) * N1 + j0);
        f32x4u zm = *(const f32x4u*)(Z + (size_t)c * N1 + j0);
        ax += vc * (zp.x - zm.x);
        ay += vc * (zp.y - zm.y);
        az += vc * (zp.z - zm.z);
        aw += vc * (zp.w - zm.w);
    }
    // combine cg pairs within each wave: lane l (<32) += lane l+32
    ax += __shfl_down(ax, 32, 64);
    ay += __shfl_down(ay, 32, 64);
    az += __shfl_down(az, 32, 64);
    aw += __shfl_down(aw, 32, 64);
    __shared__ float red[4][32][4];                // [wave][jq][component]
    const int w = t >> 6;                          // 0..3
    if ((t & 63) < 32) {
        red[w][t & 31][0] = ax; red[w][t & 31][1] = ay;
        red[w][t & 31][2] = az; red[w][t & 31][3] = aw;
    }
    __syncthreads();
    if (t < 32) {                                  // one thread per jq: sum 4 waves (= 8 cg's)
        float sx = 0.f, sy = 0.f, sz = 0.f, sw = 0.f;
        #pragma unroll
        for (int ww = 0; ww < 4; ++ww) {
            sx += red[ww][t][0]; sy += red[ww][t][1];
            sz += red[ww][t][2]; sw += red[ww][t][3];
        }
        float* o = out + (size_t)(DD - 1) * N1 + blockIdx.x * 128 + t * 4;
        atomicAdd(o + 0, scale * sx);
        atomicAdd(o + 1, scale * sy);
        atomicAdd(o + 2, scale * sz);
        atomicAdd(o + 3, scale * sw);
    }
    // tail column j = 8192 (each c-split adds its 32-c share)
    if (blockIdx.x == 0 && t == 0) {
        float lt = 0.f;
        #pragma unroll
        for (int m = 0; m < 32; ++m) {
            const int c = blockIdx.y * 32 + m;
            lt += v[c] * (Z[(size_t)(c + D) * N1 + N] - Z[(size_t)c * N1 + N]);
        }
        atomicAdd(out + (size_t)(DD - 1) * N1 + N, scale * lt);
    }
}

extern "C" void kernel_launch(void* const* d_in, const int* in_sizes, int n_in,
                              void* d_out, int out_size, void* d_ws, size_t ws_size,
                              hipStream_t stream) {
    const float* Z     = (const float*)d_in[0];
    const float* alpha = (const float*)d_in[1];
    float* out = (float*)d_out;
    float* v   = (float*)d_ws;   // D floats = 4 KB scratch

    copy_dot_rows<<<DD, 512, 0, stream>>>(Z, out, v);
    corr_kernel<<<dim3(64, 32), 256, 0, stream>>>(Z, v, alpha, out);
}